// Round 6
// baseline (21.900 us; speedup 1.0000x reference)
//
#include <hip/hip_runtime.h>
#include <hip/hip_bf16.h>
#include <cmath>

// PlotLine: 8 polylines -> 128x128 Gaussian-splatted images, tanh'd.
// draft[n,i,j] = sum_l exp(-(i-x_l)^2/2w_l) * exp(-(j-y_l)^2/2w_l); out = tanh.
// Fused, no workspace. Block = one (img, 32x16 tile), full K.
// NEW (r6): Gaussian locality — w<=3 => contributions vanish for d>10, so
// each block tests all 176 K-chunks' bboxes against its tile(+halo) and only
// processes live chunks (~15%), via a deterministic compacted list.
// Params stored SoA (x,y,cf): 6 ds_read_b128 per chunk (was 16 reads).

constexpr int IMG  = 128;
constexpr int NPTS = 32;
constexpr int TPL  = 181;           // samples per segment
constexpr int LTOT = 31 * TPL;      // 5611
constexpr int KC   = 32;            // K per MFMA chunk
constexpr int NCH  = 176;           // ceil(LTOT/KC), tail padded
constexpr int NW   = 8;             // waves per block
constexpr int TI   = 32;            // tile rows (i <-> x)
constexpr int TJ   = 16;            // tile cols (j <-> y)
constexpr float HALO = 10.0f;       // exp(-100/6)*5611 ~ 3e-4 worst-case drop

typedef __attribute__((ext_vector_type(8))) short bf16x8;
typedef __attribute__((ext_vector_type(4))) float f32x4;

__device__ inline float fast_exp2(float x) {
#if __has_builtin(__builtin_amdgcn_exp2f)
    return __builtin_amdgcn_exp2f(x);      // raw v_exp_f32; args <= 0 here
#else
    return exp2f(x);
#endif
}

__device__ inline float fast_rcp(float x) {
#if __has_builtin(__builtin_amdgcn_rcpf)
    return __builtin_amdgcn_rcpf(x);       // v_rcp_f32, ~1 ulp
#else
    return 1.0f / x;
#endif
}

// pack two positive f32 into bf16 pair (round-half-up): 2 adds + 1 v_perm
__device__ inline unsigned pack_bf16_pair(float lo, float hi) {
    unsigned ulo = __builtin_bit_cast(unsigned, lo) + 0x8000u;
    unsigned uhi = __builtin_bit_cast(unsigned, hi) + 0x8000u;
#if __has_builtin(__builtin_amdgcn_perm)
    return __builtin_amdgcn_perm(uhi, ulo, 0x07060302u);  // [ulo.hi16, uhi.hi16]
#else
    return (ulo >> 16) | (uhi & 0xFFFF0000u);
#endif
}

union Frag { bf16x8 v; unsigned u[4]; };
union F8   { float4 v[2]; float f[8]; };

__global__ __launch_bounds__(512, 1)
void plot_fused_kernel(const float* __restrict__ pts, float* __restrict__ out)
{
    const int bx   = blockIdx.x;
    const int img  = bx >> 5;           // 32 tiles per image
    const int tile = bx & 31;
    const int i0   = (tile >> 3) * TI;  // 4 row-tiles (x-dim)
    const int j0   = (tile & 7) * TJ;   // 8 col-tiles (y-dim)

    const int t   = threadIdx.x;
    const int w   = t >> 6;             // wave 0..7
    const int lid = t & 63;

    __shared__ float4 ptsh[NPTS];                  // (x, y, width, _)
    __shared__ float  xs[NW][KC], ys[NW][KC], cfs[NW][KC];
    __shared__ unsigned char livef[NCH];
    __shared__ short  livelist[NCH];
    __shared__ int    nlive_s;
    __shared__ float  red[NW][TI][TJ + 2];         // epilogue (stride 18)

    if (t < NPTS) {
        const float* p = pts + (img * NPTS + t) * 3;
        ptsh[t] = make_float4(p[0], p[1], p[2], 0.0f);
    }
    __syncthreads();

    // ---- per-chunk bbox + live flag (1 thread per chunk).
    // Samples lie on the polyline: bbox = hull{P(l0), P(l1), interior orig pt}.
    if (t < NCH) {
        const int l0 = t * KC;
        const int l1 = min(l0 + KC - 1, LTOT - 1);
        const int s0 = l0 / TPL;
        const int s1 = l1 / TPL;
        const float f0 = (float)(l0 - s0 * TPL) * (1.0f / TPL);
        const float f1 = (float)(l1 - s1 * TPL) * (1.0f / TPL);
        const float4 a0 = ptsh[s0], a1 = ptsh[s0 + 1];
        const float4 b0 = ptsh[s1], b1 = ptsh[s1 + 1];
        const float x0 = a0.x + f0 * (a1.x - a0.x);
        const float y0 = a0.y + f0 * (a1.y - a0.y);
        const float x1 = b0.x + f1 * (b1.x - b0.x);
        const float y1 = b0.y + f1 * (b1.y - b0.y);
        float xmn = fminf(x0, x1), xmx = fmaxf(x0, x1);
        float ymn = fminf(y0, y1), ymx = fmaxf(y0, y1);
        if (s1 != s0) {                 // include shared breakpoint pts[s1]
            xmn = fminf(xmn, b0.x); xmx = fmaxf(xmx, b0.x);
            ymn = fminf(ymn, b0.y); ymx = fmaxf(ymx, b0.y);
        }
        const bool live =
            (xmx >= (float)i0 - HALO) && (xmn <= (float)(i0 + TI - 1) + HALO) &&
            (ymx >= (float)j0 - HALO) && (ymn <= (float)(j0 + TJ - 1) + HALO);
        livef[t] = live ? 1 : 0;
    }
    __syncthreads();
    if (t == 0) {                       // deterministic ordered compaction
        int n = 0;
        for (int c = 0; c < NCH; ++c)
            if (livef[c]) livelist[n++] = (short)c;
        nlive_s = n;
    }
    __syncthreads();
    const int nlive = nlive_s;

    f32x4 acc0 = (f32x4)0.0f;           // rows i0..i0+15
    f32x4 acc1 = (f32x4)0.0f;           // rows i0+16..i0+31

    const float r0f = (float)(i0 + (lid & 15));
    const float r1f = r0f + 16.0f;
    const float cjf = (float)(j0 + (lid & 15));
    const int   kb  = (lid >> 4) * 8;   // k base within chunk

    for (int idx = w; idx < nlive; idx += NW) {
        const int c = livelist[idx];

        // ---- params: lanes 0..31 -> (x, y, cf) for l = c*32 + lane
        if (lid < KC) {
            const int l = c * KC + lid;
            float xv = 65536.0f, yv = 65536.0f, cf = -1.0f;   // pad -> exp 0
            if (l < LTOT) {
                const int   seg = l / TPL;                    // magic-mul
                const float ft  = (float)(l - seg * TPL) * (1.0f / TPL);
                const float4 p0 = ptsh[seg];
                const float4 p1 = ptsh[seg + 1];
                xv = p0.x + ft * (p1.x - p0.x);
                yv = p0.y + ft * (p1.y - p0.y);
                const float wv = p0.z + ft * (p1.z - p0.z);
                cf = -0.7213475204444817f * fast_rcp(wv);     // -log2(e)/(2w)
            }
            xs[w][lid] = xv; ys[w][lid] = yv; cfs[w][lid] = cf;
        }
        // per-wave LDS, intra-wave producer->consumer: lgkmcnt orders it

        // ---- 6 ds_read_b128, then 24 exp2 + 12 packs in registers
        F8 XA, YA, CF;
        XA.v[0] = *(const float4*)&xs[w][kb];  XA.v[1] = *(const float4*)&xs[w][kb + 4];
        YA.v[0] = *(const float4*)&ys[w][kb];  YA.v[1] = *(const float4*)&ys[w][kb + 4];
        CF.v[0] = *(const float4*)&cfs[w][kb]; CF.v[1] = *(const float4*)&cfs[w][kb + 4];

        Frag A0, A1, B0;
#pragma unroll
        for (int jp = 0; jp < 4; ++jp) {
            const float xa = XA.f[2 * jp], xb = XA.f[2 * jp + 1];
            const float ya = YA.f[2 * jp], yb = YA.f[2 * jp + 1];
            const float ca = CF.f[2 * jp], cb = CF.f[2 * jp + 1];
            float d;
            d = r0f - xa; const float ea0 = fast_exp2(ca * d * d);
            d = r0f - xb; const float eb0 = fast_exp2(cb * d * d);
            A0.u[jp] = pack_bf16_pair(ea0, eb0);
            d = r1f - xa; const float ea1 = fast_exp2(ca * d * d);
            d = r1f - xb; const float eb1 = fast_exp2(cb * d * d);
            A1.u[jp] = pack_bf16_pair(ea1, eb1);
            d = cjf - ya; const float ec0 = fast_exp2(ca * d * d);
            d = cjf - yb; const float ec1 = fast_exp2(cb * d * d);
            B0.u[jp] = pack_bf16_pair(ec0, ec1);
        }

        acc0 = __builtin_amdgcn_mfma_f32_16x16x32_bf16(A0.v, B0.v, acc0, 0, 0, 0);
        acc1 = __builtin_amdgcn_mfma_f32_16x16x32_bf16(A1.v, B0.v, acc1, 0, 0, 0);
    }

    // ---- epilogue: 8-wave K reduction via LDS, tanh, store
    // D layout: col = lane&15, row = (lane>>4)*4 + r   (verified round 2)
    const int drow = (lid >> 4) * 4;
    const int dcol = lid & 15;
#pragma unroll
    for (int r = 0; r < 4; ++r) {
        red[w][drow + r][dcol]      = acc0[r];
        red[w][16 + drow + r][dcol] = acc1[r];
    }
    __syncthreads();

    {
        const int rr = t >> 4;          // 0..31
        const int cc = t & 15;          // 0..15
        float s = 0.0f;
#pragma unroll
        for (int i = 0; i < NW; ++i) s += red[i][rr][cc];
        out[((size_t)img * IMG + (i0 + rr)) * IMG + (j0 + cc)] = tanhf(s);
    }
}

extern "C" void kernel_launch(void* const* d_in, const int* in_sizes, int n_in,
                              void* d_out, int out_size, void* d_ws, size_t ws_size,
                              hipStream_t stream) {
    const float* pts  = (const float*)d_in[0];
    const int    nimg = in_sizes[0] / (NPTS * 3);   // 8
    float*       out  = (float*)d_out;

    const int blocks = nimg * 32;                   // 256: one block per out-tile
    plot_fused_kernel<<<blocks, dim3(512), 0, stream>>>(pts, out);
}

// Round 7
// 15.622 us; speedup vs baseline: 1.4019x; 1.4019x over previous
//
#include <hip/hip_runtime.h>
#include <hip/hip_bf16.h>
#include <cmath>

// PlotLine: 8 polylines -> 128x128 Gaussian-splatted images, tanh'd.
// draft[n,i,j] = sum_l exp(-(i-x_l)^2/2w_l) * exp(-(j-y_l)^2/2w_l); out = tanh.
// Fused, no workspace. r7: block = one (img, 16x16 tile), 256 thr / 4 waves,
// 4 blocks/CU (launch_bounds(256,4)) for latency hiding + SIMD-level load
// balance of dense tiles. Chunk culling via bbox + deterministic BALLOT
// compaction (serial thread-0 scan removed). Register-direct bf16 MFMA.

constexpr int IMG  = 128;
constexpr int NPTS = 32;
constexpr int TPL  = 181;           // samples per segment
constexpr int LTOT = 31 * TPL;      // 5611
constexpr int KC   = 32;            // K per MFMA chunk
constexpr int NCH  = 176;           // ceil(LTOT/KC), tail padded
constexpr int NW   = 4;             // waves per block
constexpr int TI   = 16;            // tile rows (i <-> x)
constexpr int TJ   = 16;            // tile cols (j <-> y)
constexpr float HALO = 10.0f;       // worst-case dropped mass ~3e-4 << 0.02

typedef __attribute__((ext_vector_type(8))) short bf16x8;
typedef __attribute__((ext_vector_type(4))) float f32x4;

__device__ inline float fast_exp2(float x) {
#if __has_builtin(__builtin_amdgcn_exp2f)
    return __builtin_amdgcn_exp2f(x);      // raw v_exp_f32; args <= 0 here
#else
    return exp2f(x);
#endif
}

__device__ inline float fast_rcp(float x) {
#if __has_builtin(__builtin_amdgcn_rcpf)
    return __builtin_amdgcn_rcpf(x);       // v_rcp_f32, ~1 ulp
#else
    return 1.0f / x;
#endif
}

// pack two positive f32 into bf16 pair (round-half-up): 2 adds + 1 v_perm
__device__ inline unsigned pack_bf16_pair(float lo, float hi) {
    unsigned ulo = __builtin_bit_cast(unsigned, lo) + 0x8000u;
    unsigned uhi = __builtin_bit_cast(unsigned, hi) + 0x8000u;
#if __has_builtin(__builtin_amdgcn_perm)
    return __builtin_amdgcn_perm(uhi, ulo, 0x07060302u);  // [ulo.hi16, uhi.hi16]
#else
    return (ulo >> 16) | (uhi & 0xFFFF0000u);
#endif
}

union Frag { bf16x8 v; unsigned u[4]; };
union F8   { float4 v[2]; float f[8]; };

__global__ __launch_bounds__(256, 4)
void plot_fused_kernel(const float* __restrict__ pts, float* __restrict__ out)
{
    const int bx   = blockIdx.x;
    const int img  = bx >> 6;           // 64 tiles per image
    const int tile = bx & 63;
    const int i0   = (tile >> 3) * TI;  // 8 row-tiles (x-dim)
    const int j0   = (tile & 7) * TJ;   // 8 col-tiles (y-dim)

    const int t   = threadIdx.x;
    const int w   = t >> 6;             // wave 0..3
    const int lid = t & 63;

    __shared__ float4 ptsh[NPTS];                  // (x, y, width, _)
    __shared__ float  xs[NW][KC], ys[NW][KC], cfs[NW][KC];
    __shared__ unsigned long long masks[NW];       // per-wave live ballots
    __shared__ short  livelist[NCH];
    __shared__ float  red[NW][TI][TJ + 2];         // epilogue (stride 18)

    if (t < NPTS) {
        const float* p = pts + (img * NPTS + t) * 3;
        ptsh[t] = make_float4(p[0], p[1], p[2], 0.0f);
    }
    __syncthreads();

    // ---- per-chunk bbox live test (t = chunk id), ballot compaction.
    // Samples lie on the polyline: bbox = hull{P(l0), P(l1), breakpoint}.
    bool live = false;
    if (t < NCH) {
        const int l0 = t * KC;
        const int l1 = min(l0 + KC - 1, LTOT - 1);
        const int s0 = l0 / TPL;
        const int s1 = l1 / TPL;
        const float f0 = (float)(l0 - s0 * TPL) * (1.0f / TPL);
        const float f1 = (float)(l1 - s1 * TPL) * (1.0f / TPL);
        const float4 a0 = ptsh[s0], a1 = ptsh[s0 + 1];
        const float4 b0 = ptsh[s1], b1 = ptsh[s1 + 1];
        const float x0 = a0.x + f0 * (a1.x - a0.x);
        const float y0 = a0.y + f0 * (a1.y - a0.y);
        const float x1 = b0.x + f1 * (b1.x - b0.x);
        const float y1 = b0.y + f1 * (b1.y - b0.y);
        float xmn = fminf(x0, x1), xmx = fmaxf(x0, x1);
        float ymn = fminf(y0, y1), ymx = fmaxf(y0, y1);
        if (s1 != s0) {                 // include shared breakpoint pts[s1]
            xmn = fminf(xmn, b0.x); xmx = fmaxf(xmx, b0.x);
            ymn = fminf(ymn, b0.y); ymx = fmaxf(ymx, b0.y);
        }
        live = (xmx >= (float)i0 - HALO) && (xmn <= (float)(i0 + TI - 1) + HALO)
            && (ymx >= (float)j0 - HALO) && (ymn <= (float)(j0 + TJ - 1) + HALO);
    }
    {
        const unsigned long long m = __ballot(live);
        if (lid == 0) masks[w] = m;
        __syncthreads();
        if (live) {
            const int base = (w == 0) ? 0
                           : (w == 1) ? __popcll(masks[0])
                           : __popcll(masks[0]) + __popcll(masks[1]);
            const int pos = base + __popcll(m & ((1ull << lid) - 1ull));
            livelist[pos] = (short)t;
        }
    }
    __syncthreads();
    const int nlive = __popcll(masks[0]) + __popcll(masks[1]) + __popcll(masks[2]);

    f32x4 acc = (f32x4)0.0f;

    const float r0f = (float)(i0 + (lid & 15));   // A row coordinate
    const float cjf = (float)(j0 + (lid & 15));   // B col coordinate
    const int   kb  = (lid >> 4) * 8;             // k base within chunk

    for (int idx = w; idx < nlive; idx += NW) {
        const int c = livelist[idx];

        // ---- params: lanes 0..31 -> (x, y, cf) for l = c*32 + lane
        if (lid < KC) {
            const int l = c * KC + lid;
            float xv = 65536.0f, yv = 65536.0f, cf = -1.0f;   // pad -> exp 0
            if (l < LTOT) {
                const int   seg = l / TPL;                    // magic-mul
                const float ft  = (float)(l - seg * TPL) * (1.0f / TPL);
                const float4 p0 = ptsh[seg];
                const float4 p1 = ptsh[seg + 1];
                xv = p0.x + ft * (p1.x - p0.x);
                yv = p0.y + ft * (p1.y - p0.y);
                const float wv = p0.z + ft * (p1.z - p0.z);
                cf = -0.7213475204444817f * fast_rcp(wv);     // -log2(e)/(2w)
            }
            xs[w][lid] = xv; ys[w][lid] = yv; cfs[w][lid] = cf;
        }
        // per-wave LDS, intra-wave producer->consumer: lgkmcnt orders it

        // ---- 6 ds_read_b128, 16 exp2 + 8 packs, 1 MFMA
        F8 XA, YA, CF;
        XA.v[0] = *(const float4*)&xs[w][kb];  XA.v[1] = *(const float4*)&xs[w][kb + 4];
        YA.v[0] = *(const float4*)&ys[w][kb];  YA.v[1] = *(const float4*)&ys[w][kb + 4];
        CF.v[0] = *(const float4*)&cfs[w][kb]; CF.v[1] = *(const float4*)&cfs[w][kb + 4];

        Frag A, B;
#pragma unroll
        for (int jp = 0; jp < 4; ++jp) {
            const float xa = XA.f[2 * jp], xb = XA.f[2 * jp + 1];
            const float ya = YA.f[2 * jp], yb = YA.f[2 * jp + 1];
            const float ca = CF.f[2 * jp], cb = CF.f[2 * jp + 1];
            float d;
            d = r0f - xa; const float ea = fast_exp2(ca * d * d);
            d = r0f - xb; const float eb = fast_exp2(cb * d * d);
            A.u[jp] = pack_bf16_pair(ea, eb);
            d = cjf - ya; const float ec = fast_exp2(ca * d * d);
            d = cjf - yb; const float ed = fast_exp2(cb * d * d);
            B.u[jp] = pack_bf16_pair(ec, ed);
        }

        acc = __builtin_amdgcn_mfma_f32_16x16x32_bf16(A.v, B.v, acc, 0, 0, 0);
    }

    // ---- epilogue: 4-wave K reduction via LDS, tanh, store
    // D layout: col = lane&15, row = (lane>>4)*4 + r   (verified round 2)
    const int drow = (lid >> 4) * 4;
    const int dcol = lid & 15;
#pragma unroll
    for (int r = 0; r < 4; ++r)
        red[w][drow + r][dcol] = acc[r];
    __syncthreads();

    {
        const int rr = t >> 4;          // 0..15
        const int cc = t & 15;          // 0..15
        float s = 0.0f;
#pragma unroll
        for (int i = 0; i < NW; ++i) s += red[i][rr][cc];
        out[((size_t)img * IMG + (i0 + rr)) * IMG + (j0 + cc)] = tanhf(s);
    }
}

extern "C" void kernel_launch(void* const* d_in, const int* in_sizes, int n_in,
                              void* d_out, int out_size, void* d_ws, size_t ws_size,
                              hipStream_t stream) {
    const float* pts  = (const float*)d_in[0];
    const int    nimg = in_sizes[0] / (NPTS * 3);   // 8
    float*       out  = (float*)d_out;

    const int blocks = nimg * 64;                   // 512: one block per 16x16 tile
    plot_fused_kernel<<<blocks, dim3(256), 0, stream>>>(pts, out);
}

// Round 8
// 12.565 us; speedup vs baseline: 1.7429x; 1.2433x over previous
//
#include <hip/hip_runtime.h>
#include <hip/hip_bf16.h>
#include <cmath>

// PlotLine: 8 polylines -> 128x128 Gaussian-splatted images, tanh'd.
// draft[n,i,j] = sum_l exp(-(i-x_l)^2/2w_l) * exp(-(j-y_l)^2/2w_l); out = tanh.
// Fused, no workspace. r8: block = one (img, 16x16 tile), 512 thr / 8 waves
// (K split 8-ways), launch_bounds(512,2) -> 16 waves/CU. Chunk culling via
// bbox + ballot compaction. Register-direct bf16 MFMA fragments (raw v_exp,
// +0x8000 round + v_perm pack). Deterministic everywhere.

constexpr int IMG  = 128;
constexpr int NPTS = 32;
constexpr int TPL  = 181;           // samples per segment
constexpr int LTOT = 31 * TPL;      // 5611
constexpr int KC   = 32;            // K per MFMA chunk
constexpr int NCH  = 176;           // ceil(LTOT/KC), tail padded
constexpr int NW   = 8;             // waves per block
constexpr int TI   = 16;            // tile rows (i <-> x)
constexpr int TJ   = 16;            // tile cols (j <-> y)
constexpr float HALO = 10.0f;       // worst-case dropped mass ~3e-4 << 0.02

typedef __attribute__((ext_vector_type(8))) short bf16x8;
typedef __attribute__((ext_vector_type(4))) float f32x4;

__device__ inline float fast_exp2(float x) {
#if __has_builtin(__builtin_amdgcn_exp2f)
    return __builtin_amdgcn_exp2f(x);      // raw v_exp_f32; args <= 0 here
#else
    return exp2f(x);
#endif
}

__device__ inline float fast_rcp(float x) {
#if __has_builtin(__builtin_amdgcn_rcpf)
    return __builtin_amdgcn_rcpf(x);       // v_rcp_f32, ~1 ulp
#else
    return 1.0f / x;
#endif
}

// pack two positive f32 into bf16 pair (round-half-up): 2 adds + 1 v_perm
__device__ inline unsigned pack_bf16_pair(float lo, float hi) {
    unsigned ulo = __builtin_bit_cast(unsigned, lo) + 0x8000u;
    unsigned uhi = __builtin_bit_cast(unsigned, hi) + 0x8000u;
#if __has_builtin(__builtin_amdgcn_perm)
    return __builtin_amdgcn_perm(uhi, ulo, 0x07060302u);  // [ulo.hi16, uhi.hi16]
#else
    return (ulo >> 16) | (uhi & 0xFFFF0000u);
#endif
}

union Frag { bf16x8 v; unsigned u[4]; };
union F8   { float4 v[2]; float f[8]; };

__global__ __launch_bounds__(512, 2)
void plot_fused_kernel(const float* __restrict__ pts, float* __restrict__ out)
{
    const int bx   = blockIdx.x;
    const int img  = bx >> 6;           // 64 tiles per image
    const int tile = bx & 63;
    const int i0   = (tile >> 3) * TI;  // 8 row-tiles (x-dim)
    const int j0   = (tile & 7) * TJ;   // 8 col-tiles (y-dim)

    const int t   = threadIdx.x;
    const int w   = t >> 6;             // wave 0..7
    const int lid = t & 63;

    __shared__ float4 ptsh[NPTS];                  // (x, y, width, _)
    __shared__ float  xs[NW][KC], ys[NW][KC], cfs[NW][KC];
    __shared__ unsigned long long masks[NW];       // per-wave live ballots
    __shared__ short  livelist[NCH];
    __shared__ float  red[NW][TI][TJ + 2];         // epilogue (stride 18)

    if (t < NPTS) {
        const float* p = pts + (img * NPTS + t) * 3;
        ptsh[t] = make_float4(p[0], p[1], p[2], 0.0f);
    }
    __syncthreads();

    // ---- per-chunk bbox live test (t = chunk id), ballot compaction.
    // Samples lie on the polyline: bbox = hull{P(l0), P(l1), breakpoint}.
    bool live = false;
    if (t < NCH) {
        const int l0 = t * KC;
        const int l1 = min(l0 + KC - 1, LTOT - 1);
        const int s0 = l0 / TPL;
        const int s1 = l1 / TPL;
        const float f0 = (float)(l0 - s0 * TPL) * (1.0f / TPL);
        const float f1 = (float)(l1 - s1 * TPL) * (1.0f / TPL);
        const float4 a0 = ptsh[s0], a1 = ptsh[s0 + 1];
        const float4 b0 = ptsh[s1], b1 = ptsh[s1 + 1];
        const float x0 = a0.x + f0 * (a1.x - a0.x);
        const float y0 = a0.y + f0 * (a1.y - a0.y);
        const float x1 = b0.x + f1 * (b1.x - b0.x);
        const float y1 = b0.y + f1 * (b1.y - b0.y);
        float xmn = fminf(x0, x1), xmx = fmaxf(x0, x1);
        float ymn = fminf(y0, y1), ymx = fmaxf(y0, y1);
        if (s1 != s0) {                 // include shared breakpoint pts[s1]
            xmn = fminf(xmn, b0.x); xmx = fmaxf(xmx, b0.x);
            ymn = fminf(ymn, b0.y); ymx = fmaxf(ymx, b0.y);
        }
        live = (xmx >= (float)i0 - HALO) && (xmn <= (float)(i0 + TI - 1) + HALO)
            && (ymx >= (float)j0 - HALO) && (ymn <= (float)(j0 + TJ - 1) + HALO);
    }
    {
        const unsigned long long m = __ballot(live);
        if (lid == 0) masks[w] = m;
        __syncthreads();
        if (live) {
            int base = 0;
            for (int i = 0; i < 8; ++i)               // w is wave-uniform
                if (i < w) base += __popcll(masks[i]);
            const int pos = base + __popcll(m & ((1ull << lid) - 1ull));
            livelist[pos] = (short)t;
        }
    }
    __syncthreads();
    int nlive = 0;
#pragma unroll
    for (int i = 0; i < NW; ++i) nlive += __popcll(masks[i]);

    f32x4 acc = (f32x4)0.0f;

    const float r0f = (float)(i0 + (lid & 15));   // A row coordinate
    const float cjf = (float)(j0 + (lid & 15));   // B col coordinate
    const int   kb  = (lid >> 4) * 8;             // k base within chunk

    for (int idx = w; idx < nlive; idx += NW) {
        const int c = livelist[idx];

        // ---- params: lanes 0..31 -> (x, y, cf) for l = c*32 + lane
        if (lid < KC) {
            const int l = c * KC + lid;
            float xv = 65536.0f, yv = 65536.0f, cf = -1.0f;   // pad -> exp 0
            if (l < LTOT) {
                const int   seg = l / TPL;                    // magic-mul
                const float ft  = (float)(l - seg * TPL) * (1.0f / TPL);
                const float4 p0 = ptsh[seg];
                const float4 p1 = ptsh[seg + 1];
                xv = p0.x + ft * (p1.x - p0.x);
                yv = p0.y + ft * (p1.y - p0.y);
                const float wv = p0.z + ft * (p1.z - p0.z);
                cf = -0.7213475204444817f * fast_rcp(wv);     // -log2(e)/(2w)
            }
            xs[w][lid] = xv; ys[w][lid] = yv; cfs[w][lid] = cf;
        }
        // per-wave LDS, intra-wave producer->consumer: lgkmcnt orders it

        // ---- 6 ds_read_b128, 16 exp2 + 8 packs, 1 MFMA
        F8 XA, YA, CF;
        XA.v[0] = *(const float4*)&xs[w][kb];  XA.v[1] = *(const float4*)&xs[w][kb + 4];
        YA.v[0] = *(const float4*)&ys[w][kb];  YA.v[1] = *(const float4*)&ys[w][kb + 4];
        CF.v[0] = *(const float4*)&cfs[w][kb]; CF.v[1] = *(const float4*)&cfs[w][kb + 4];

        Frag A, B;
#pragma unroll
        for (int jp = 0; jp < 4; ++jp) {
            const float xa = XA.f[2 * jp], xb = XA.f[2 * jp + 1];
            const float ya = YA.f[2 * jp], yb = YA.f[2 * jp + 1];
            const float ca = CF.f[2 * jp], cb = CF.f[2 * jp + 1];
            float d;
            d = r0f - xa; const float ea = fast_exp2(ca * d * d);
            d = r0f - xb; const float eb = fast_exp2(cb * d * d);
            A.u[jp] = pack_bf16_pair(ea, eb);
            d = cjf - ya; const float ec = fast_exp2(ca * d * d);
            d = cjf - yb; const float ed = fast_exp2(cb * d * d);
            B.u[jp] = pack_bf16_pair(ec, ed);
        }

        acc = __builtin_amdgcn_mfma_f32_16x16x32_bf16(A.v, B.v, acc, 0, 0, 0);
    }

    // ---- epilogue: 8-wave K reduction via LDS, tanh, store
    // D layout: col = lane&15, row = (lane>>4)*4 + r   (verified round 2)
    const int drow = (lid >> 4) * 4;
    const int dcol = lid & 15;
#pragma unroll
    for (int r = 0; r < 4; ++r)
        red[w][drow + r][dcol] = acc[r];
    __syncthreads();

    if (t < TI * TJ) {
        const int rr = t >> 4;          // 0..15
        const int cc = t & 15;          // 0..15
        float s = 0.0f;
#pragma unroll
        for (int i = 0; i < NW; ++i) s += red[i][rr][cc];
        out[((size_t)img * IMG + (i0 + rr)) * IMG + (j0 + cc)] = tanhf(s);
    }
}

extern "C" void kernel_launch(void* const* d_in, const int* in_sizes, int n_in,
                              void* d_out, int out_size, void* d_ws, size_t ws_size,
                              hipStream_t stream) {
    const float* pts  = (const float*)d_in[0];
    const int    nimg = in_sizes[0] / (NPTS * 3);   // 8
    float*       out  = (float*)d_out;

    const int blocks = nimg * 64;                   // 512: one block per 16x16 tile
    plot_fused_kernel<<<blocks, dim3(512), 0, stream>>>(pts, out);
}